// Round 7
// baseline (241.677 us; speedup 1.0000x reference)
//
#include <hip/hip_runtime.h>

#define N_COL 256
#define N_ROW 256
#define N_NEUR (N_COL * N_ROW)      // 65536
#define N_PTS  (64 * 1001)          // 64064
#define BATCH  512
#define N_WORDS (N_NEUR / 32)       // 2048 u32 = 8 KB bitmap

typedef float f32x4 __attribute__((ext_vector_type(4)));

// ws layout: [0, 2048) u32 touched-bitmap (rotated indexing) | [2048] int count
// (ws re-poisoned to 0xAA before every timed call -> init rebuilds both)

// ---------------------------------------------------------------------------
// Kernel 1: zero the 8 KB bitmap + count. (trivial, ~1 us)
// ---------------------------------------------------------------------------
__global__ void init_bitmap(unsigned* __restrict__ bitmap, int* __restrict__ count) {
    int k = blockIdx.x * blockDim.x + threadIdx.x;   // 2048 threads
    bitmap[k] = 0u;
    if (k == 0) *count = 0;
}

// ---------------------------------------------------------------------------
// Kernel 2: scatter touched cells into the ROTATED bitmap.
// Reference: touched cell (ix,iy) -> m[ix][iy]=0; rot[i][j]=m[j][255-i]
//   => flat rotated index k = (255-iy)*256 + ix.
// atomicOr old-value test -> exactly ONE incrementer per distinct cell, so
// count = #distinct touched cells and sum(mask) = 65536 - count (exact
// integer; matches the reference's f32 sum of 0/1 values bit-for-bit).
// ---------------------------------------------------------------------------
__global__ void scatter_touch(const float* __restrict__ ax,
                              const float* __restrict__ ay,
                              unsigned* __restrict__ bitmap,
                              int* __restrict__ count) {
    int p = blockIdx.x * blockDim.x + threadIdx.x;
    if (p >= N_PTS) return;
    float fx = ax[p] * (float)N_COL;
    float fy = ay[p] * (float)N_ROW;
    float cx = floorf(fx);
    float cy = floorf(fy);
    float rx = fx - cx;
    float ry = fy - cy;
    bool in_box = (rx >= 0.25f) && (rx <= 0.75f) && (ry >= 0.25f) && (ry <= 0.75f);
    if (in_box) {
        int ix = min(max((int)cx, 0), N_COL - 1);
        int iy = min(max((int)cy, 0), N_ROW - 1);
        int k = (N_ROW - 1 - iy) * N_COL + ix;        // rotated position
        unsigned bit = 1u << (k & 31);
        unsigned old = atomicOr(&bitmap[k >> 5], bit);
        if ((old & bit) == 0) atomicAdd(count, 1);    // first toucher only
    }
}

// ---------------------------------------------------------------------------
// Kernel 3: out = in * mask * scale. Bitmap is 8 KB -> L1-resident; zero
// L2/HBM traffic for the mask. float4 nontemporal streaming for in/out.
// scale replicates reference arithmetic exactly (all ops exact for
// integer s <= 65536): rate = 1 - s/65536 ; scale = 1/(1-rate).
// mask==0 lanes: reference gives in*0.0*scale = +/-0.0; we emit the same
// magnitude (|diff| = 0), via v * 0.0f * scale ordering-free select.
// ---------------------------------------------------------------------------
__global__ void apply_mask(const float* __restrict__ in,
                           const unsigned* __restrict__ bitmap,
                           const int* __restrict__ count_ptr,
                           float* __restrict__ out) {
    const unsigned total4 = (unsigned)BATCH * (N_NEUR / 4);   // 8,388,608
    float s = (float)(N_NEUR - *count_ptr);
    float rate = 1.0f - s / (float)N_NEUR;
    float scale = 1.0f / (1.0f - rate);

    const f32x4* __restrict__ in4 = (const f32x4*)in;
    f32x4* __restrict__ out4      = (f32x4*)out;

    unsigned stride = gridDim.x * blockDim.x;
    for (unsigned idx = blockIdx.x * blockDim.x + threadIdx.x;
         idx < total4; idx += stride) {
        unsigned k0 = (idx * 4) & (N_NEUR - 1);   // first of 4 consecutive cells
        unsigned w = bitmap[k0 >> 5];             // 4 bits share one word (4|32)
        unsigned b = k0 & 31;
        f32x4 v = __builtin_nontemporal_load(&in4[idx]);
        f32x4 r;
        r.x = ((w >> (b + 0)) & 1u) ? v.x * 0.0f * scale : v.x * scale;
        r.y = ((w >> (b + 1)) & 1u) ? v.y * 0.0f * scale : v.y * scale;
        r.z = ((w >> (b + 2)) & 1u) ? v.z * 0.0f * scale : v.z * scale;
        r.w = ((w >> (b + 3)) & 1u) ? v.w * 0.0f * scale : v.w * scale;
        __builtin_nontemporal_store(r, &out4[idx]);
    }
}

extern "C" void kernel_launch(void* const* d_in, const int* in_sizes, int n_in,
                              void* d_out, int out_size, void* d_ws, size_t ws_size,
                              hipStream_t stream) {
    const float* input = (const float*)d_in[0];
    const float* ax    = (const float*)d_in[1];
    const float* ay    = (const float*)d_in[2];
    float* out = (float*)d_out;

    unsigned* bitmap = (unsigned*)d_ws;
    int*      count  = (int*)d_ws + N_WORDS;

    init_bitmap<<<N_WORDS / 256, 256, 0, stream>>>(bitmap, count);
    scatter_touch<<<(N_PTS + 255) / 256, 256, 0, stream>>>(ax, ay, bitmap, count);
    apply_mask<<<2048, 256, 0, stream>>>(input, bitmap, count, out);
}